// Round 1
// baseline (482.668 us; speedup 1.0000x reference)
//
#include <hip/hip_runtime.h>

#define DIM 128
#define BN_EPS_F 1e-5f

// ---------------- CSR build ----------------

__global__ void hist_kernel(const int* __restrict__ dst, int* __restrict__ counts, int E) {
    int e = blockIdx.x * blockDim.x + threadIdx.x;
    if (e < E) atomicAdd(&counts[dst[e]], 1);
}

// single-block exclusive scan over up to 16384 counts
__global__ __launch_bounds__(1024) void scan_kernel(const int* __restrict__ counts,
                                                    int* __restrict__ rowptr, int n) {
    __shared__ int sums[1024];
    const int CH = 16;
    int t = threadIdx.x;
    int base = t * CH;
    int local[CH];
    int s = 0;
#pragma unroll
    for (int i = 0; i < CH; i++) {
        int idx = base + i;
        local[i] = s;
        if (idx < n) s += counts[idx];
    }
    sums[t] = s;
    __syncthreads();
    for (int off = 1; off < 1024; off <<= 1) {
        int v = (t >= off) ? sums[t - off] : 0;
        __syncthreads();
        sums[t] += v;
        __syncthreads();
    }
    int prev = (t > 0) ? sums[t - 1] : 0;
#pragma unroll
    for (int i = 0; i < CH; i++) {
        int idx = base + i;
        if (idx < n) rowptr[idx] = prev + local[i];
    }
    if (t == 1023) rowptr[n] = sums[1023];
}

__global__ void fill_kernel(const int* __restrict__ src, const int* __restrict__ dst,
                            const int* __restrict__ rowptr, int* __restrict__ cursor,
                            int* __restrict__ srcsorted, int E) {
    int e = blockIdx.x * blockDim.x + threadIdx.x;
    if (e < E) {
        int d = dst[e];
        int pos = rowptr[d] + atomicAdd(&cursor[d], 1);
        srcsorted[pos] = src[e];
    }
}

__global__ void init_ab_kernel(float* __restrict__ ab) {
    int t = threadIdx.x;
    ab[t] = 1.0f;
    ab[DIM + t] = 0.0f;
}

// ---------------- fused affine(prev-BN) + GIN aggregate ----------------
// hp_out[d] = a*( (1+eps)*hp_in[d] + sum_{s in in(d)} hp_in[s] ) + (1+eps+deg)*b
// One 64-lane wave per node: lane = slot(2) x quad(32). Each slot walks every
// other in-edge, loading a float4 of the source row (512B/row, coalesced).
__global__ __launch_bounds__(256) void gather_kernel(const float* __restrict__ hin,
                                                     float* __restrict__ hout,
                                                     const int* __restrict__ rowptr,
                                                     const int* __restrict__ srcs,
                                                     const float* __restrict__ ab, int n) {
    int wave = blockIdx.x * (blockDim.x >> 6) + (threadIdx.x >> 6);
    if (wave >= n) return;
    int lane = threadIdx.x & 63;
    int slot = lane >> 5;   // 0 or 1
    int quad = lane & 31;   // float4 index within the 128-wide row
    int start = rowptr[wave];
    int end = rowptr[wave + 1];

    float ax = 0.f, ay = 0.f, az = 0.f, aw = 0.f;
    for (int e = start + slot; e < end; e += 2) {
        int s = srcs[e];
        const float4 v = *(const float4*)(hin + (size_t)s * DIM + quad * 4);
        ax += v.x; ay += v.y; az += v.z; aw += v.w;
    }
    // combine the two slots (lane ^ 32)
    ax += __shfl_xor(ax, 32);
    ay += __shfl_xor(ay, 32);
    az += __shfl_xor(az, 32);
    aw += __shfl_xor(aw, 32);

    const float4 self = *(const float4*)(hin + (size_t)wave * DIM + quad * 4);
    float degp1 = 1.0f + (float)(end - start);  // (1+eps)+deg, eps=0
    const float4 a = *(const float4*)(ab + quad * 4);
    const float4 b = *(const float4*)(ab + DIM + quad * 4);

    float4 r;
    r.x = a.x * (self.x + ax) + degp1 * b.x;
    r.y = a.y * (self.y + ay) + degp1 * b.y;
    r.z = a.z * (self.z + az) + degp1 * b.z;
    r.w = a.w * (self.w + aw) + degp1 * b.w;
    if (slot == 0) *(float4*)(hout + (size_t)wave * DIM + quad * 4) = r;
}

// ---------------- column stats: partial sums / sumsq ----------------
__global__ __launch_bounds__(256) void stats_kernel(const float* __restrict__ h,
                                                    float* __restrict__ psum,
                                                    float* __restrict__ psq,
                                                    int n, int rows_per_block) {
    __shared__ float4 ls[8][32];
    __shared__ float4 lq[8][32];
    int tid = threadIdx.x;
    int rowsub = tid >> 5;  // 0..7
    int quad = tid & 31;
    int r0 = blockIdx.x * rows_per_block;
    int r1 = r0 + rows_per_block;
    if (r1 > n) r1 = n;
    float sx = 0.f, sy = 0.f, sz = 0.f, sw = 0.f;
    float qx = 0.f, qy = 0.f, qz = 0.f, qw = 0.f;
    for (int r = r0 + rowsub; r < r1; r += 8) {
        const float4 v = *(const float4*)(h + (size_t)r * DIM + quad * 4);
        sx += v.x; sy += v.y; sz += v.z; sw += v.w;
        qx += v.x * v.x; qy += v.y * v.y; qz += v.z * v.z; qw += v.w * v.w;
    }
    ls[rowsub][quad] = make_float4(sx, sy, sz, sw);
    lq[rowsub][quad] = make_float4(qx, qy, qz, qw);
    __syncthreads();
    if (rowsub == 0) {
        for (int i = 1; i < 8; i++) {
            float4 a = ls[i][quad];
            sx += a.x; sy += a.y; sz += a.z; sw += a.w;
            float4 c = lq[i][quad];
            qx += c.x; qy += c.y; qz += c.z; qw += c.w;
        }
        *(float4*)(psum + (size_t)blockIdx.x * DIM + quad * 4) = make_float4(sx, sy, sz, sw);
        *(float4*)(psq + (size_t)blockIdx.x * DIM + quad * 4) = make_float4(qx, qy, qz, qw);
    }
}

__global__ __launch_bounds__(128) void finalize_kernel(const float* __restrict__ psum,
                                                       const float* __restrict__ psq,
                                                       const float* __restrict__ gamma,
                                                       const float* __restrict__ beta,
                                                       float* __restrict__ ab,
                                                       int nblocks, float inv_n) {
    int c = threadIdx.x;  // 0..127
    float s = 0.f, q = 0.f;
    for (int p = 0; p < nblocks; p++) {
        s += psum[(size_t)p * DIM + c];
        q += psq[(size_t)p * DIM + c];
    }
    float mu = s * inv_n;
    float var = q * inv_n - mu * mu;
    float a = gamma[c] * rsqrtf(var + BN_EPS_F);
    ab[c] = a;
    ab[DIM + c] = beta[c] - mu * a;
}

// ---------------- final affine apply (layer 3) ----------------
__global__ void apply_kernel(const float* __restrict__ hp, const float* __restrict__ ab,
                             float* __restrict__ out, int total4) {
    int i = blockIdx.x * blockDim.x + threadIdx.x;
    if (i < total4) {
        int quad = i & 31;
        float4 v = ((const float4*)hp)[i];
        const float4 a = *(const float4*)(ab + quad * 4);
        const float4 b = *(const float4*)(ab + DIM + quad * 4);
        float4 r;
        r.x = a.x * v.x + b.x;
        r.y = a.y * v.y + b.y;
        r.z = a.z * v.z + b.z;
        r.w = a.w * v.w + b.w;
        ((float4*)out)[i] = r;
    }
}

extern "C" void kernel_launch(void* const* d_in, const int* in_sizes, int n_in,
                              void* d_out, int out_size, void* d_ws, size_t ws_size,
                              hipStream_t stream) {
    const float* x = (const float*)d_in[0];
    const float* gamma = (const float*)d_in[1];
    const float* beta = (const float*)d_in[2];
    const int* src = (const int*)d_in[3];
    const int* dst = (const int*)d_in[4];
    float* out = (float*)d_out;

    const int n = in_sizes[0] / DIM;   // 10000
    const int E = in_sizes[3];         // 640000

    char* ws = (char*)d_ws;
    auto alloc = [&](size_t bytes) -> char* {
        char* p = ws;
        ws += (bytes + 255) / 256 * 256;
        return p;
    };
    int* rowptr = (int*)alloc((size_t)(n + 1) * 4);
    int* counts = (int*)alloc((size_t)n * 4);
    int* cursor = (int*)alloc((size_t)n * 4);
    int* srcsorted = (int*)alloc((size_t)E * 4);
    float* ab = (float*)alloc(2 * DIM * 4);
    const int SBLK = 125;
    const int rows_per_block = (n + SBLK - 1) / SBLK;
    float* psum = (float*)alloc((size_t)SBLK * DIM * 4);
    float* psq = (float*)alloc((size_t)SBLK * DIM * 4);
    float* hp0 = (float*)alloc((size_t)n * DIM * 4);
    float* hp1 = (float*)alloc((size_t)n * DIM * 4);

    hipMemsetAsync(counts, 0, (size_t)n * 4, stream);
    hipMemsetAsync(cursor, 0, (size_t)n * 4, stream);

    hist_kernel<<<(E + 255) / 256, 256, 0, stream>>>(dst, counts, E);
    scan_kernel<<<1, 1024, 0, stream>>>(counts, rowptr, n);
    fill_kernel<<<(E + 255) / 256, 256, 0, stream>>>(src, dst, rowptr, cursor, srcsorted, E);
    init_ab_kernel<<<1, DIM, 0, stream>>>(ab);

    const float* hin = x;
    float* bufs[2] = {hp0, hp1};
    for (int l = 0; l < 4; l++) {
        float* hout = bufs[l & 1];
        gather_kernel<<<(n + 3) / 4, 256, 0, stream>>>(hin, hout, rowptr, srcsorted, ab, n);
        stats_kernel<<<SBLK, 256, 0, stream>>>(hout, psum, psq, n, rows_per_block);
        finalize_kernel<<<1, DIM, 0, stream>>>(psum, psq, gamma + (size_t)l * DIM,
                                               beta + (size_t)l * DIM, ab, SBLK, 1.0f / n);
        hin = hout;
    }
    apply_kernel<<<((n * DIM / 4) + 255) / 256, 256, 0, stream>>>(bufs[3 & 1], ab, out,
                                                                  n * DIM / 4);
}

// Round 2
// 388.001 us; speedup vs baseline: 1.2440x; 1.2440x over previous
//
#include <hip/hip_runtime.h>

#define DIM 128
#define BN_EPS_F 1e-5f

// ---------------- CSR build ----------------

__global__ void hist_kernel(const int* __restrict__ dst, int* __restrict__ counts, int E) {
    int e = blockIdx.x * blockDim.x + threadIdx.x;
    if (e < E) atomicAdd(&counts[dst[e]], 1);
}

// single-block exclusive scan over up to 16384 counts
__global__ __launch_bounds__(1024) void scan_kernel(const int* __restrict__ counts,
                                                    int* __restrict__ rowptr, int n) {
    __shared__ int sums[1024];
    const int CH = 16;
    int t = threadIdx.x;
    int base = t * CH;
    int local[CH];
    int s = 0;
#pragma unroll
    for (int i = 0; i < CH; i++) {
        int idx = base + i;
        local[i] = s;
        if (idx < n) s += counts[idx];
    }
    sums[t] = s;
    __syncthreads();
    for (int off = 1; off < 1024; off <<= 1) {
        int v = (t >= off) ? sums[t - off] : 0;
        __syncthreads();
        sums[t] += v;
        __syncthreads();
    }
    int prev = (t > 0) ? sums[t - 1] : 0;
#pragma unroll
    for (int i = 0; i < CH; i++) {
        int idx = base + i;
        if (idx < n) rowptr[idx] = prev + local[i];
    }
    if (t == 1023) rowptr[n] = sums[1023];
}

// fill: pos = rowptr[d] + (--counts[d]); counts ends all-zero (reused as ticket)
__global__ void fill_kernel(const int* __restrict__ src, const int* __restrict__ dst,
                            const int* __restrict__ rowptr, int* __restrict__ counts,
                            int* __restrict__ srcsorted, int E) {
    int e = blockIdx.x * blockDim.x + threadIdx.x;
    if (e < E) {
        int d = dst[e];
        int c = atomicSub(&counts[d], 1);
        srcsorted[rowptr[d] + c - 1] = src[e];
    }
}

// ---------------- fused affine(prev-BN) + GIN aggregate ----------------
// hout[d] = a*( hin[d] + sum_{s in in(d)} hin[s] ) + (1+deg)*b   (eps=0)
// One 64-lane wave per node: lane = slot(2) x quad(32). Each slot walks every
// other in-edge; unrolled x4 with independent accumulators -> 8 rows in
// flight per wave (latency hiding).
__global__ __launch_bounds__(256) void gather_kernel(const float* __restrict__ hin,
                                                     float* __restrict__ hout,
                                                     const int* __restrict__ rowptr,
                                                     const int* __restrict__ srcs,
                                                     const float* __restrict__ ab, int n,
                                                     int use_ab) {
    int wave = blockIdx.x * (blockDim.x >> 6) + (threadIdx.x >> 6);
    if (wave >= n) return;
    int lane = threadIdx.x & 63;
    int slot = lane >> 5;   // 0 or 1
    int quad = lane & 31;   // float4 index within the 128-wide row
    int start = rowptr[wave];
    int end = rowptr[wave + 1];

    float4 a0 = {0.f, 0.f, 0.f, 0.f}, a1 = a0, a2 = a0, a3 = a0;

    int e = start + slot;
    for (; e + 6 < end; e += 8) {
        int s0 = srcs[e];
        int s1 = srcs[e + 2];
        int s2 = srcs[e + 4];
        int s3 = srcs[e + 6];
        float4 v0 = *(const float4*)(hin + (size_t)s0 * DIM + quad * 4);
        float4 v1 = *(const float4*)(hin + (size_t)s1 * DIM + quad * 4);
        float4 v2 = *(const float4*)(hin + (size_t)s2 * DIM + quad * 4);
        float4 v3 = *(const float4*)(hin + (size_t)s3 * DIM + quad * 4);
        a0.x += v0.x; a0.y += v0.y; a0.z += v0.z; a0.w += v0.w;
        a1.x += v1.x; a1.y += v1.y; a1.z += v1.z; a1.w += v1.w;
        a2.x += v2.x; a2.y += v2.y; a2.z += v2.z; a2.w += v2.w;
        a3.x += v3.x; a3.y += v3.y; a3.z += v3.z; a3.w += v3.w;
    }
    for (; e < end; e += 2) {
        int s = srcs[e];
        float4 v = *(const float4*)(hin + (size_t)s * DIM + quad * 4);
        a0.x += v.x; a0.y += v.y; a0.z += v.z; a0.w += v.w;
    }
    float ax = (a0.x + a1.x) + (a2.x + a3.x);
    float ay = (a0.y + a1.y) + (a2.y + a3.y);
    float az = (a0.z + a1.z) + (a2.z + a3.z);
    float aw = (a0.w + a1.w) + (a2.w + a3.w);

    // combine the two slots (lane ^ 32)
    ax += __shfl_xor(ax, 32);
    ay += __shfl_xor(ay, 32);
    az += __shfl_xor(az, 32);
    aw += __shfl_xor(aw, 32);

    const float4 self = *(const float4*)(hin + (size_t)wave * DIM + quad * 4);
    float degp1 = 1.0f + (float)(end - start);
    float4 a = {1.f, 1.f, 1.f, 1.f};
    float4 b = {0.f, 0.f, 0.f, 0.f};
    if (use_ab) {
        a = *(const float4*)(ab + quad * 4);
        b = *(const float4*)(ab + DIM + quad * 4);
    }

    float4 r;
    r.x = a.x * (self.x + ax) + degp1 * b.x;
    r.y = a.y * (self.y + ay) + degp1 * b.y;
    r.z = a.z * (self.z + az) + degp1 * b.z;
    r.w = a.w * (self.w + aw) + degp1 * b.w;
    if (slot == 0) *(float4*)(hout + (size_t)wave * DIM + quad * 4) = r;
}

// ---------------- column stats + fused last-block finalize ----------------
__global__ __launch_bounds__(256) void stats_kernel(const float* __restrict__ h,
                                                    float* __restrict__ psum,
                                                    float* __restrict__ psq,
                                                    const float* __restrict__ gamma,
                                                    const float* __restrict__ beta,
                                                    float* __restrict__ ab,
                                                    int* __restrict__ ticket,
                                                    int n, int rows_per_block, int nblocks,
                                                    float inv_n) {
    __shared__ float4 ls[8][32];
    __shared__ float4 lq[8][32];
    int tid = threadIdx.x;
    int rowsub = tid >> 5;  // 0..7
    int quad = tid & 31;
    int r0 = blockIdx.x * rows_per_block;
    int r1 = r0 + rows_per_block;
    if (r1 > n) r1 = n;
    float sx = 0.f, sy = 0.f, sz = 0.f, sw = 0.f;
    float qx = 0.f, qy = 0.f, qz = 0.f, qw = 0.f;
    for (int r = r0 + rowsub; r < r1; r += 8) {
        const float4 v = *(const float4*)(h + (size_t)r * DIM + quad * 4);
        sx += v.x; sy += v.y; sz += v.z; sw += v.w;
        qx += v.x * v.x; qy += v.y * v.y; qz += v.z * v.z; qw += v.w * v.w;
    }
    ls[rowsub][quad] = make_float4(sx, sy, sz, sw);
    lq[rowsub][quad] = make_float4(qx, qy, qz, qw);
    __syncthreads();
    if (rowsub == 0) {
        for (int i = 1; i < 8; i++) {
            float4 t1 = ls[i][quad];
            sx += t1.x; sy += t1.y; sz += t1.z; sw += t1.w;
            float4 t2 = lq[i][quad];
            qx += t2.x; qy += t2.y; qz += t2.z; qw += t2.w;
        }
        *(float4*)(psum + (size_t)blockIdx.x * DIM + quad * 4) = make_float4(sx, sy, sz, sw);
        *(float4*)(psq + (size_t)blockIdx.x * DIM + quad * 4) = make_float4(qx, qy, qz, qw);
    }
    // last-block finalize
    __threadfence();
    __shared__ int lastflag;
    if (tid == 0) lastflag = (atomicAdd(ticket, 1) == nblocks - 1) ? 1 : 0;
    __syncthreads();
    if (!lastflag) return;
    if (tid == 0) *ticket = 0;  // reset for next layer's dispatch
    __threadfence();
    int c = tid & 127;
    int half = tid >> 7;  // 0/1
    float s = 0.f, q = 0.f;
    for (int p = half; p < nblocks; p += 2) {
        s += psum[(size_t)p * DIM + c];
        q += psq[(size_t)p * DIM + c];
    }
    __shared__ float sh_s[256], sh_q[256];
    sh_s[tid] = s;
    sh_q[tid] = q;
    __syncthreads();
    if (tid < 128) {
        s = sh_s[tid] + sh_s[tid + 128];
        q = sh_q[tid] + sh_q[tid + 128];
        float mu = s * inv_n;
        float var = q * inv_n - mu * mu;
        float av = gamma[c] * rsqrtf(var + BN_EPS_F);
        ab[c] = av;
        ab[DIM + c] = beta[c] - mu * av;
    }
}

// ---------------- final affine apply (layer 3) ----------------
__global__ void apply_kernel(const float* __restrict__ hp, const float* __restrict__ ab,
                             float* __restrict__ out, int total4) {
    int i = blockIdx.x * blockDim.x + threadIdx.x;
    if (i < total4) {
        int quad = i & 31;
        float4 v = ((const float4*)hp)[i];
        const float4 a = *(const float4*)(ab + quad * 4);
        const float4 b = *(const float4*)(ab + DIM + quad * 4);
        float4 r;
        r.x = a.x * v.x + b.x;
        r.y = a.y * v.y + b.y;
        r.z = a.z * v.z + b.z;
        r.w = a.w * v.w + b.w;
        ((float4*)out)[i] = r;
    }
}

extern "C" void kernel_launch(void* const* d_in, const int* in_sizes, int n_in,
                              void* d_out, int out_size, void* d_ws, size_t ws_size,
                              hipStream_t stream) {
    const float* x = (const float*)d_in[0];
    const float* gamma = (const float*)d_in[1];
    const float* beta = (const float*)d_in[2];
    const int* src = (const int*)d_in[3];
    const int* dst = (const int*)d_in[4];
    float* out = (float*)d_out;

    const int n = in_sizes[0] / DIM;   // 10000
    const int E = in_sizes[3];         // 640000

    char* ws = (char*)d_ws;
    auto alloc = [&](size_t bytes) -> char* {
        char* p = ws;
        ws += (bytes + 255) / 256 * 256;
        return p;
    };
    int* rowptr = (int*)alloc((size_t)(n + 1) * 4);
    int* counts = (int*)alloc((size_t)n * 4);   // doubles as finalize ticket (counts[0])
    int* srcsorted = (int*)alloc((size_t)E * 4);
    float* ab = (float*)alloc(2 * DIM * 4);
    const int SBLK = 125;
    const int rows_per_block = (n + SBLK - 1) / SBLK;
    float* psum = (float*)alloc((size_t)SBLK * DIM * 4);
    float* psq = (float*)alloc((size_t)SBLK * DIM * 4);
    float* hp0 = (float*)alloc((size_t)n * DIM * 4);
    float* hp1 = (float*)alloc((size_t)n * DIM * 4);

    hipMemsetAsync(counts, 0, (size_t)n * 4, stream);

    hist_kernel<<<(E + 255) / 256, 256, 0, stream>>>(dst, counts, E);
    scan_kernel<<<1, 1024, 0, stream>>>(counts, rowptr, n);
    fill_kernel<<<(E + 255) / 256, 256, 0, stream>>>(src, dst, rowptr, counts, srcsorted, E);
    // after fill, counts[] is all zero -> counts[0] is the zeroed ticket

    const float* hin = x;
    float* bufs[2] = {hp0, hp1};
    for (int l = 0; l < 4; l++) {
        float* hout = bufs[l & 1];
        gather_kernel<<<(n + 3) / 4, 256, 0, stream>>>(hin, hout, rowptr, srcsorted, ab, n,
                                                       l == 0 ? 0 : 1);
        stats_kernel<<<SBLK, 256, 0, stream>>>(hout, psum, psq, gamma + (size_t)l * DIM,
                                               beta + (size_t)l * DIM, ab, &counts[0], n,
                                               rows_per_block, SBLK, 1.0f / n);
        hin = hout;
    }
    apply_kernel<<<((n * DIM / 4) + 255) / 256, 256, 0, stream>>>(bufs[3 & 1], ab, out,
                                                                  n * DIM / 4);
}